// Round 8
// baseline (155.802 us; speedup 1.0000x reference)
//
#include <hip/hip_runtime.h>

// R7: gather latency attack, same diagnosis as R6 post-mortem (latency-bound,
// 2.9 TB/s of a 34 TB/s L2 pipe, 20% occupancy).
//  - c-half split: 128-thr blocks, LDS 19KB -> 8 blocks/CU (2x waves/CU)
//  - list entries pulled 64-at-a-time with ONE stride-2 ds_read, then shfl
//    broadcast: removes the 120-cyc ds_read from every point's address chain
//  - batch-4 prefetch + run-merge + exactly-once coalesced flush (R6, kept)

constexpr int D = 40, H = 32, W = 88, HW = H * W;       // 2816
constexpr int C = 128, NCAM = 6;
constexpr int BEV = 125, NBINS = BEV * BEV;             // 15625
constexpr int NCOLS = NCAM * HW;                        // 16896
constexpr int SEGMAX = 128;                             // target points/segment
constexpr int SLOTS  = 56;                              // max segments/row
constexpr int LISTCAP = 448;                            // max seg points ~300

typedef __attribute__((ext_vector_type(8))) unsigned short us8;
typedef __attribute__((ext_vector_type(4))) float f4;

__device__ __forceinline__ unsigned short f2bf(float x) {   // RNE
    unsigned u = __float_as_uint(x);
    return (unsigned short)((u + 0x7FFF + ((u >> 16) & 1)) >> 16);
}
__device__ __forceinline__ float b2f(unsigned short u) {
    return __uint_as_float(((unsigned)u) << 16);
}

// ---------------------------------------------------------------- constexpr tables
struct Tabs { short XP[D][126]; short YP[D][126]; };

constexpr Tabs make_tabs() {
    Tabs t{};
    for (int d = 0; d < D; ++d) {
        int dep = d + 2;
        int cntx[126] = {};
        for (int w = 0; w < W; ++w) {
            float xd = (float)(w * dep);
            float gx = xd / 3567.0f * 100.0f - 50.0f;
            int ix = (int)((gx + 50.0f) / 0.8f);
            if (ix < 125) cntx[ix]++;
        }
        t.XP[d][0] = 0;
        for (int X = 0; X < 125; ++X) t.XP[d][X + 1] = (short)(t.XP[d][X] + cntx[X]);
        int cnty[126] = {};
        for (int h = 0; h < H; ++h) {
            float yd = (float)(h * dep);
            float gy = yd / 1271.0f * 100.0f - 50.0f;
            int iy = (int)((gy + 50.0f) / 0.8f);
            if (iy < 125) cnty[iy]++;
        }
        t.YP[d][0] = 0;
        for (int Y = 0; Y < 125; ++Y) t.YP[d][Y + 1] = (short)(t.YP[d][Y] + cnty[Y]);
    }
    return t;
}
__device__ const Tabs g_tab = make_tabs();

// ---------------------------------------------------------------- D1: mega
constexpr int SCHED_BLOCKS = BEV;                  // 125
constexpr int PACK_BLOCKS  = (C / 8) * (HW / 32);  // 1408
constexpr int SMAX_BLOCKS  = NCOLS / 256;          // 66
constexpr int MEGA_BLOCKS  = SCHED_BLOCKS + PACK_BLOCKS + SMAX_BLOCKS;

__global__ void __launch_bounds__(256) mega_kernel(
        const float* __restrict__ feat,     // [NCAM][C][HW]
        const float* __restrict__ logits,   // [NCAM][D][HW]
        float* __restrict__ probs_t,
        unsigned short* __restrict__ feat_p,
        unsigned* __restrict__ segs) {      // [BEV][SLOTS]
    __shared__ __align__(16) float tile[NCAM * 8 * 37];   // pack staging
    __shared__ int cnt[125];
    __shared__ unsigned rowsegs[SLOTS];
    int b = blockIdx.x, t = threadIdx.x;

    if (b < SCHED_BLOCKS) {
        int iy = b;
        if (t < 125) {
            int X = t, s = 0;
#pragma unroll 8
            for (int d = 0; d < D; ++d) {
                int xc = g_tab.XP[d][X + 1] - g_tab.XP[d][X];
                int yc = g_tab.YP[d][iy + 1] - g_tab.YP[d][iy];
                s += xc * yc;
            }
            cnt[X] = s;
        }
        if (t < SLOTS) rowsegs[t] = 0xFFFFFFFFu;
        __syncthreads();
        if (t == 0) {                                    // greedy cut
            int ns = 0, X0 = 0, run = 0;
            for (int X = 0; X < 125; ++X) {
                int cX = cnt[X];
                if (X > X0 && ns < SLOTS - 1 &&
                    (run + cX > SEGMAX || X - X0 >= 32)) {
                    rowsegs[ns++] = ((unsigned)iy << 16) | ((unsigned)X0 << 8) | (unsigned)X;
                    X0 = X; run = 0;
                }
                run += cX;
            }
            rowsegs[ns++] = ((unsigned)iy << 16) | ((unsigned)X0 << 8) | 125u;
        }
        __syncthreads();
        if (t < SLOTS) segs[iy * SLOTS + t] = rowsegs[t];

    } else if (b < SCHED_BLOCKS + PACK_BLOCKS) {
        int b2 = b - SCHED_BLOCKS;
        int c0  = (b2 / 88) * 8;
        int hw0 = (b2 % 88) * 32;
        int cq = t >> 5, hwL = t & 31;
#pragma unroll
        for (int n = 0; n < NCAM; ++n)
            tile[(n * 8 + cq) * 37 + hwL] =
                feat[((size_t)(n * C + c0 + cq)) * HW + hw0 + hwL];
        __syncthreads();
        int hl = t >> 3, cL = t & 7;
        us8 v;
#pragma unroll
        for (int n = 0; n < NCAM; ++n)
            v[n] = f2bf(tile[(n * 8 + cL) * 37 + hl]);
        v[6] = 0; v[7] = 0;
        *(us8*)(feat_p + ((size_t)(hw0 + hl) * C + (c0 + cL)) * 8) = v;

    } else {
        int col = (b - SCHED_BLOCKS - PACK_BLOCKS) * 256 + t;   // < NCOLS exact
        int n  = col / HW;
        int hw = col - n * HW;
        const float* src = logits + ((size_t)n * D) * HW + hw;
        float v[D];
        float m = -3.402823466e+38f;
#pragma unroll
        for (int d = 0; d < D; ++d) {
            v[d] = src[(size_t)d * HW];
            m = fmaxf(m, v[d]);
        }
        float s = 0.f;
#pragma unroll
        for (int d = 0; d < D; ++d) { v[d] = expf(v[d] - m); s += v[d]; }
        float inv = 1.0f / s;
#pragma unroll
        for (int d = 0; d < D; ++d)
            probs_t[(size_t)((d << 12) | hw) * 8 + n] = v[d] * inv;
    }
}

// ---------------------------------------------------------------- D2: gather
// Block = (segment slot, c-half). 128 thr = 2 waves = 2 dgroups; lane = c
// within the half. Wave 0 enumerates the list; wave 1 zeros the tiles.
// Consume: per 64 points ONE stride-2 ds_read preloads entries into a VGPR,
// per-point broadcast via shfl (VALU) -> address chain is shfl + global load.
__global__ void __launch_bounds__(128, 8) gather_kernel(
        const unsigned short* __restrict__ feat_p,   // [hw][c][8] bf16
        const float* __restrict__ probs_t,           // [(d<<12)|hw][8] f32
        const unsigned* __restrict__ segs,
        float* __restrict__ out) {                   // [C][NBINS]
    __shared__ float T[2][32][66];                   // 16.9 KB
    __shared__ unsigned list[LISTCAP];
    __shared__ int Pcnt;
    int slot  = blockIdx.x >> 1;
    int chalf = blockIdx.x & 1;
    unsigned dsc = (unsigned)__builtin_amdgcn_readfirstlane((int)segs[slot]);
    if (dsc == 0xFFFFFFFFu) return;
    int iy = dsc >> 16, X0 = (dsc >> 8) & 0xFF, X1 = dsc & 0xFF;
    int width = X1 - X0;
    int t = threadIdx.x;

    if (t < 64) {                                    // wave 0: enumerate
        int d = t;
        if (d < D) {
            int off = 0;
            for (int dd = 0; dd < d; ++dd)
                off += (g_tab.YP[dd][iy + 1] - g_tab.YP[dd][iy]) *
                       (g_tab.XP[dd][X1] - g_tab.XP[dd][X0]);
            int hb = g_tab.YP[d][iy], he = g_tab.YP[d][iy + 1];
            int p = off;
            for (int bl = 0; bl < width; ++bl) {
                int wb = g_tab.XP[d][X0 + bl], we = g_tab.XP[d][X0 + bl + 1];
                for (int h = hb; h < he; ++h)
                    for (int w = wb; w < we; ++w)
                        list[p++] = ((unsigned)bl << 18) | ((unsigned)d << 12)
                                  | (unsigned)(h * W + w);
            }
            if (d == D - 1) Pcnt = p;
        }
    } else {                                         // wave 1: zero tiles
        float* Tf = &T[0][0][0];
        for (int i = t - 64; i < 2 * 32 * 66; i += 64) Tf[i] = 0.f;
    }
    __syncthreads();

    int P = Pcnt;
    int lane = t & 63, dg = t >> 6;
    int c = chalf * 64 + lane;
    float* Tp = &T[dg][0][0];

    int npts = (P - dg + 1) >> 1;                    // this dgroup's count
    float racc = 0.f;
    int rbl = -1;
    for (int kb = 0; kb < npts; kb += 64) {
        // one coalesced LDS read covers the next 64 points of this dgroup
        int kidx = kb + lane;
        int myent = (int)list[min(dg + 2 * kidx, LISTCAP - 1)];
        int kk64 = min(64, npts - kb);
        for (int k0 = 0; k0 < kk64; k0 += 4) {
            int kk = min(4, kk64 - k0);
            unsigned pk[4]; us8 fv[4]; f4 pa[4], pb[4];
#pragma unroll
            for (int j = 0; j < 4; ++j) if (j < kk) {
                pk[j] = (unsigned)__shfl(myent, k0 + j);
                unsigned hw = pk[j] & 0xFFFu;
                fv[j] = *(const us8*)(feat_p + ((size_t)hw * C + (unsigned)c) * 8);
                const float* pp = probs_t + ((size_t)(pk[j] & 0x3FFFFu) << 3);
                pa[j] = *(const f4*)pp;
                pb[j] = *(const f4*)(pp + 4);
            }
#pragma unroll
            for (int j = 0; j < 4; ++j) if (j < kk) {
                float s = pa[j].x * b2f(fv[j][0]) + pa[j].y * b2f(fv[j][1])
                        + pa[j].z * b2f(fv[j][2]) + pa[j].w * b2f(fv[j][3])
                        + pb[j].x * b2f(fv[j][4]) + pb[j].y * b2f(fv[j][5]);
                int bl = (int)(pk[j] >> 18);         // wave-uniform
                if (bl != rbl) {                     // run-merge
                    if (rbl >= 0) Tp[rbl * 66 + lane] += racc;
                    rbl = bl; racc = s;
                } else {
                    racc += s;
                }
            }
        }
    }
    if (rbl >= 0) Tp[rbl * 66 + lane] += racc;
    __syncthreads();

    int binbase = iy * BEV + X0;
    for (int it = 0; it < 16; ++it) {                // coalesced 128B runs
        int bl = t & 31, ccl = it * 4 + (t >> 5);    // ccl in [0,64)
        if (bl < width)
            out[(size_t)(chalf * 64 + ccl) * NBINS + binbase + bl]
                = T[0][bl][ccl] + T[1][bl][ccl];
    }
}

// ---------------------------------------------------------------- launch
extern "C" void kernel_launch(void* const* d_in, const int* in_sizes, int n_in,
                              void* d_out, int out_size, void* d_ws, size_t ws_size,
                              hipStream_t stream) {
    const float* img_feat     = (const float*)d_in[0];
    const float* depth_logits = (const float*)d_in[1];
    float* out = (float*)d_out;

    char* p = (char*)d_ws;
    float*          probs_t = (float*)p;          p += (size_t)D * 4096 * 8 * 4;  // 5.24 MB
    unsigned short* feat_p  = (unsigned short*)p; p += (size_t)HW * C * 8 * 2;    // 5.77 MB
    unsigned*       segs    = (unsigned*)p;       p += (size_t)BEV * SLOTS * 4;   // 28 KB

    mega_kernel<<<MEGA_BLOCKS, 256, 0, stream>>>(
        img_feat, depth_logits, probs_t, feat_p, segs);
    gather_kernel<<<BEV * SLOTS * 2, 128, 0, stream>>>(feat_p, probs_t, segs, out);
}

// Round 10
// 125.353 us; speedup vs baseline: 1.2429x; 1.2429x over previous
//
#include <hip/hip_runtime.h>

// R9: compile-time compacted segment worklist. R7 post-mortem: gather launched
// 14000 blocks, 87% empty -> resident window held ~1 BUSY block/CU (dispatch
// is in-order) -> no latency hiding, 79us. Segmentation is input-independent,
// so: constexpr segment table (row, X-range<=16, d-range, count<=176), grid =
// NSEG*2 exactly, every block busy. Heavy single bins d-split (flush via
// atomicAdd onto zeroed out; others exactly-once plain store). Consume =
// R7-proven shfl-broadcast batch-4. Fixed ~75us/call harness floor identified
// across R0-R7; kernel-side target is gather+mega.

constexpr int D = 40, H = 32, W = 88, HW = H * W;       // 2816
constexpr int C = 128, NCAM = 6;
constexpr int BEV = 125, NBINS = BEV * BEV;             // 15625
constexpr int NCOLS = NCAM * HW;                        // 16896
constexpr int LISTCAP = 192;                            // max seg count 176

typedef __attribute__((ext_vector_type(8))) unsigned short us8;
typedef __attribute__((ext_vector_type(4))) float f4;

__device__ __forceinline__ unsigned short f2bf(float x) {   // RNE
    unsigned u = __float_as_uint(x);
    return (unsigned short)((u + 0x7FFF + ((u >> 16) & 1)) >> 16);
}
__device__ __forceinline__ float b2f(unsigned short u) {
    return __uint_as_float(((unsigned)u) << 16);
}

// ---------------------------------------------------------------- constexpr tables
// Compile-time IEEE fp32 == device __f*_rn sequence (verified R5-R7).
struct Tabs { short XP[D][126]; short YP[D][126]; };
constexpr Tabs make_tabs() {
    Tabs t{};
    for (int d = 0; d < D; ++d) {
        int dep = d + 2;
        int cntx[126] = {};
        for (int w = 0; w < W; ++w) {
            float gx = (float)(w * dep) / 3567.0f * 100.0f - 50.0f;
            int ix = (int)((gx + 50.0f) / 0.8f);
            if (ix < 125) cntx[ix]++;
        }
        t.XP[d][0] = 0;
        for (int X = 0; X < 125; ++X) t.XP[d][X + 1] = (short)(t.XP[d][X] + cntx[X]);
        int cnty[126] = {};
        for (int h = 0; h < H; ++h) {
            float gy = (float)(h * dep) / 1271.0f * 100.0f - 50.0f;
            int iy = (int)((gy + 50.0f) / 0.8f);
            if (iy < 125) cnty[iy]++;
        }
        t.YP[d][0] = 0;
        for (int Y = 0; Y < 125; ++Y) t.YP[d][Y + 1] = (short)(t.YP[d][Y] + cnty[Y]);
    }
    return t;
}
__device__ const Tabs g_tab = make_tabs();

// ---------------------------------------------------------------- constexpr segments
// a: iy<<16 | X0<<8 | X1 ; b: split<<31 | d0<<25 | d1<<19 | count
struct SegTable { unsigned a[4096]; unsigned b[4096]; int n; };

constexpr SegTable make_segs() {
    SegTable S{};
    Tabs t = make_tabs();
    int ns = 0;
    for (int iy = 0; iy < 125; ++iy) {
        int cnt[125] = {};
        for (int d = 0; d < D; ++d) {               // skip inactive d: cheap
            int yc = t.YP[d][iy + 1] - t.YP[d][iy];
            if (yc == 0) continue;
            for (int X = 0; X < 125; ++X)
                cnt[X] += (t.XP[d][X + 1] - t.XP[d][X]) * yc;
        }
        int X = 0;
        while (X < 125) {
            if (cnt[X] > 176) {                      // lone heavy bin: d-split
                int d0 = 0;
                while (d0 < D) {
                    int run = 0, d1 = d0;
                    while (d1 < D) {
                        int piece = (t.XP[d1][X + 1] - t.XP[d1][X]) *
                                    (t.YP[d1][iy + 1] - t.YP[d1][iy]);
                        if (d1 > d0 && run + piece > 128) break;
                        run += piece; ++d1;
                    }
                    if (run > 0) {
                        S.a[ns] = ((unsigned)iy << 16) | ((unsigned)X << 8) | (unsigned)(X + 1);
                        S.b[ns] = (1u << 31) | ((unsigned)d0 << 25) | ((unsigned)d1 << 19) | (unsigned)run;
                        ++ns;
                    }
                    d0 = d1;
                }
                ++X;
            } else {
                int X0 = X, run = 0;
                while (X < 125 && (X - X0) < 16 && cnt[X] <= 176 &&
                       (X == X0 || run + cnt[X] <= 128)) {
                    run += cnt[X]; ++X;
                }
                if (run > 0) {
                    S.a[ns] = ((unsigned)iy << 16) | ((unsigned)X0 << 8) | (unsigned)X;
                    S.b[ns] = ((unsigned)0 << 25) | ((unsigned)D << 19) | (unsigned)run;
                    ++ns;
                }
            }
        }
    }
    S.n = ns;
    return S;
}
constexpr SegTable g_ct = make_segs();
constexpr int NSEG = g_ct.n;
static_assert(NSEG > 0 && NSEG <= 4096, "seg table overflow");
__device__ const SegTable g_segs = g_ct;

// ---------------------------------------------------------------- D1: mega
// blocks [0,1408)     : pack feat -> bf16 [hw][c][8]
// blocks [1408,1474)  : softmax -> probs_t [(d<<12)|hw][8] fp32
// blocks [1474,1963)  : zero out
constexpr int PACK_BLOCKS = (C / 8) * (HW / 32);   // 1408
constexpr int SMAX_BLOCKS = NCOLS / 256;           // 66
constexpr int ZERO_TOTAL  = C * NBINS / 4;         // 500000 f4
constexpr int ZERO_BLOCKS = (ZERO_TOTAL + 1023) / 1024;  // 489
constexpr int MEGA_BLOCKS = PACK_BLOCKS + SMAX_BLOCKS + ZERO_BLOCKS;

__global__ void __launch_bounds__(256) mega_kernel(
        const float* __restrict__ feat,     // [NCAM][C][HW]
        const float* __restrict__ logits,   // [NCAM][D][HW]
        float* __restrict__ probs_t,
        unsigned short* __restrict__ feat_p,
        float* __restrict__ out) {
    __shared__ __align__(16) float tile[NCAM * 8 * 37];
    int b = blockIdx.x, t = threadIdx.x;

    if (b < PACK_BLOCKS) {
        int c0  = (b / 88) * 8;
        int hw0 = (b % 88) * 32;
        int cq = t >> 5, hwL = t & 31;
#pragma unroll
        for (int n = 0; n < NCAM; ++n)
            tile[(n * 8 + cq) * 37 + hwL] =
                feat[((size_t)(n * C + c0 + cq)) * HW + hw0 + hwL];
        __syncthreads();
        int hl = t >> 3, cL = t & 7;
        us8 v;
#pragma unroll
        for (int n = 0; n < NCAM; ++n)
            v[n] = f2bf(tile[(n * 8 + cL) * 37 + hl]);
        v[6] = 0; v[7] = 0;
        *(us8*)(feat_p + ((size_t)(hw0 + hl) * C + (c0 + cL)) * 8) = v;

    } else if (b < PACK_BLOCKS + SMAX_BLOCKS) {
        int col = (b - PACK_BLOCKS) * 256 + t;       // < NCOLS exact
        int n  = col / HW;
        int hw = col - n * HW;
        const float* src = logits + ((size_t)n * D) * HW + hw;
        float v[D];
        float m = -3.402823466e+38f;
#pragma unroll
        for (int d = 0; d < D; ++d) {
            v[d] = src[(size_t)d * HW];
            m = fmaxf(m, v[d]);
        }
        float s = 0.f;
#pragma unroll
        for (int d = 0; d < D; ++d) { v[d] = expf(v[d] - m); s += v[d]; }
        float inv = 1.0f / s;
#pragma unroll
        for (int d = 0; d < D; ++d)
            probs_t[(size_t)((d << 12) | hw) * 8 + n] = v[d] * inv;

    } else {
        int base = (b - PACK_BLOCKS - SMAX_BLOCKS) * 1024;
#pragma unroll
        for (int k = 0; k < 4; ++k) {
            int i = base + k * 256 + t;
            if (i < ZERO_TOTAL) ((f4*)out)[i] = f4{0.f, 0.f, 0.f, 0.f};
        }
    }
}

// ---------------------------------------------------------------- D2: gather
// Grid = NSEG*2 (seg, chalf) — every block busy. 128 thr = 2 waves = 2
// dgroups; lane = c within half. Wave 0 enumerates the seg's point list
// (d-range aware) into LDS; wave 1 zeros both tiles. Consume: one coalesced
// ds_read per 64 points + shfl broadcast, batch-4 prefetch, run-merge into
// per-dgroup LDS tile. Flush: plain store (exactly once) or atomicAdd for
// d-split segments (out pre-zeroed in mega).
__global__ void __launch_bounds__(128, 8) gather_kernel(
        const unsigned short* __restrict__ feat_p,   // [hw][c][8] bf16
        const float* __restrict__ probs_t,           // [(d<<12)|hw][8] f32
        float* __restrict__ out) {                   // [C][NBINS]
    __shared__ float T[2][16][66];                   // 8.25 KB
    __shared__ unsigned list[LISTCAP];
    int slot  = blockIdx.x >> 1;
    int chalf = blockIdx.x & 1;
    unsigned da = g_segs.a[slot], db = g_segs.b[slot];
    int iy = da >> 16, X0 = (da >> 8) & 0xFF, X1 = da & 0xFF;
    int width = X1 - X0;
    bool split = (db >> 31) != 0;
    int d0 = (db >> 25) & 0x3F, d1 = (db >> 19) & 0x3F;
    int P  = (int)(db & 0x7FFFF);
    int t = threadIdx.x;

    if (t < 64) {                                    // wave 0: enumerate
        int d = d0 + t;
        if (d < d1) {
            int off = 0;
            for (int dd = d0; dd < d; ++dd)
                off += (g_tab.YP[dd][iy + 1] - g_tab.YP[dd][iy]) *
                       (g_tab.XP[dd][X1] - g_tab.XP[dd][X0]);
            int hb = g_tab.YP[d][iy], he = g_tab.YP[d][iy + 1];
            int p = off;
            for (int bl = 0; bl < width; ++bl) {
                int wb = g_tab.XP[d][X0 + bl], we = g_tab.XP[d][X0 + bl + 1];
                for (int h = hb; h < he; ++h)
                    for (int w = wb; w < we; ++w)
                        list[p++] = ((unsigned)bl << 18) | ((unsigned)d << 12)
                                  | (unsigned)(h * W + w);
            }
        }
    } else {                                         // wave 1: zero tiles
        float* Tf = &T[0][0][0];
        for (int i = t - 64; i < 2 * 16 * 66; i += 64) Tf[i] = 0.f;
    }
    __syncthreads();

    int lane = t & 63, dg = t >> 6;
    int c = chalf * 64 + lane;
    float* Tp = &T[dg][0][0];

    int npts = (P - dg + 1) >> 1;                    // this dgroup's count
    float racc = 0.f;
    int rbl = -1;
    for (int kb = 0; kb < npts; kb += 64) {
        int kidx = kb + lane;
        int myent = (int)list[min(dg + 2 * kidx, LISTCAP - 1)];
        int kk64 = min(64, npts - kb);
        for (int k0 = 0; k0 < kk64; k0 += 4) {
            int kk = min(4, kk64 - k0);
            unsigned pk[4]; us8 fv[4]; f4 pa[4], pb[4];
#pragma unroll
            for (int j = 0; j < 4; ++j) if (j < kk) {
                pk[j] = (unsigned)__shfl(myent, k0 + j);
                unsigned hw = pk[j] & 0xFFFu;
                fv[j] = *(const us8*)(feat_p + ((size_t)hw * C + (unsigned)c) * 8);
                const float* pp = probs_t + ((size_t)(pk[j] & 0x3FFFFu) << 3);
                pa[j] = *(const f4*)pp;
                pb[j] = *(const f4*)(pp + 4);
            }
#pragma unroll
            for (int j = 0; j < 4; ++j) if (j < kk) {
                float s = pa[j].x * b2f(fv[j][0]) + pa[j].y * b2f(fv[j][1])
                        + pa[j].z * b2f(fv[j][2]) + pa[j].w * b2f(fv[j][3])
                        + pb[j].x * b2f(fv[j][4]) + pb[j].y * b2f(fv[j][5]);
                int bl = (int)(pk[j] >> 18);         // wave-uniform
                if (bl != rbl) {                     // run-merge
                    if (rbl >= 0) Tp[rbl * 66 + lane] += racc;
                    rbl = bl; racc = s;
                } else {
                    racc += s;
                }
            }
        }
    }
    if (rbl >= 0) Tp[rbl * 66 + lane] += racc;
    __syncthreads();

    int binbase = iy * BEV + X0;
#pragma unroll
    for (int it = 0; it < 8; ++it) {                 // 16 bl x 8 cc per iter
        int bl = t & 15, cc = it * 8 + (t >> 4);     // cc in [0,64)
        if (bl < width) {
            float v = T[0][bl][cc] + T[1][bl][cc];
            float* dst = &out[(size_t)(chalf * 64 + cc) * NBINS + binbase + bl];
            if (split) atomicAdd(dst, v);
            else       *dst = v;
        }
    }
}

// ---------------------------------------------------------------- launch
extern "C" void kernel_launch(void* const* d_in, const int* in_sizes, int n_in,
                              void* d_out, int out_size, void* d_ws, size_t ws_size,
                              hipStream_t stream) {
    const float* img_feat     = (const float*)d_in[0];
    const float* depth_logits = (const float*)d_in[1];
    float* out = (float*)d_out;

    char* p = (char*)d_ws;
    float*          probs_t = (float*)p;          p += (size_t)D * 4096 * 8 * 4;  // 5.24 MB
    unsigned short* feat_p  = (unsigned short*)p; p += (size_t)HW * C * 8 * 2;    // 5.77 MB

    mega_kernel<<<MEGA_BLOCKS, 256, 0, stream>>>(
        img_feat, depth_logits, probs_t, feat_p, out);
    gather_kernel<<<NSEG * 2, 128, 0, stream>>>(feat_p, probs_t, out);
}

// Round 11
// 124.969 us; speedup vs baseline: 1.2467x; 1.0031x over previous
//
#include <hip/hip_runtime.h>

// R10: R9 + three latency fixes on gather (48us, 14% of L2 BW, occ 36%):
//  1) __launch_bounds__(128,4): R9's (128,8) capped VGPR at 64 (VGPR_Count=32!)
//     while residency was block-limited at 8 blocks/CU = 4 waves/EU anyway.
//  2) modulo-2 software pipeline (group=3): fetch B while consuming A ->
//     ~9 loads in flight steady-state; next-window entry ds_read hoisted.
//  3) compile-time segment sort (heavy-first) -> smoother tail.

constexpr int D = 40, H = 32, W = 88, HW = H * W;       // 2816
constexpr int C = 128, NCAM = 6;
constexpr int BEV = 125, NBINS = BEV * BEV;             // 15625
constexpr int NCOLS = NCAM * HW;                        // 16896
constexpr int LISTCAP = 192;                            // max seg count 176

typedef __attribute__((ext_vector_type(8))) unsigned short us8;
typedef __attribute__((ext_vector_type(4))) float f4;

__device__ __forceinline__ unsigned short f2bf(float x) {   // RNE
    unsigned u = __float_as_uint(x);
    return (unsigned short)((u + 0x7FFF + ((u >> 16) & 1)) >> 16);
}
__device__ __forceinline__ float b2f(unsigned short u) {
    return __uint_as_float(((unsigned)u) << 16);
}

// ---------------------------------------------------------------- constexpr tables
struct Tabs { short XP[D][126]; short YP[D][126]; };
constexpr Tabs make_tabs() {
    Tabs t{};
    for (int d = 0; d < D; ++d) {
        int dep = d + 2;
        int cntx[126] = {};
        for (int w = 0; w < W; ++w) {
            float gx = (float)(w * dep) / 3567.0f * 100.0f - 50.0f;
            int ix = (int)((gx + 50.0f) / 0.8f);
            if (ix < 125) cntx[ix]++;
        }
        t.XP[d][0] = 0;
        for (int X = 0; X < 125; ++X) t.XP[d][X + 1] = (short)(t.XP[d][X] + cntx[X]);
        int cnty[126] = {};
        for (int h = 0; h < H; ++h) {
            float gy = (float)(h * dep) / 1271.0f * 100.0f - 50.0f;
            int iy = (int)((gy + 50.0f) / 0.8f);
            if (iy < 125) cnty[iy]++;
        }
        t.YP[d][0] = 0;
        for (int Y = 0; Y < 125; ++Y) t.YP[d][Y + 1] = (short)(t.YP[d][Y] + cnty[Y]);
    }
    return t;
}
__device__ const Tabs g_tab = make_tabs();

// ---------------------------------------------------------------- constexpr segments
// a: iy<<16 | X0<<8 | X1 ; b: split<<31 | d0<<25 | d1<<19 | count
struct SegTable { unsigned a[4096]; unsigned b[4096]; int n; };

constexpr SegTable make_segs() {
    SegTable S{};
    Tabs t = make_tabs();
    int ns = 0;
    for (int iy = 0; iy < 125; ++iy) {
        int cnt[125] = {};
        for (int d = 0; d < D; ++d) {
            int yc = t.YP[d][iy + 1] - t.YP[d][iy];
            if (yc == 0) continue;
            for (int X = 0; X < 125; ++X)
                cnt[X] += (t.XP[d][X + 1] - t.XP[d][X]) * yc;
        }
        int X = 0;
        while (X < 125) {
            if (cnt[X] > 176) {                      // lone heavy bin: d-split
                int d0 = 0;
                while (d0 < D) {
                    int run = 0, d1 = d0;
                    while (d1 < D) {
                        int piece = (t.XP[d1][X + 1] - t.XP[d1][X]) *
                                    (t.YP[d1][iy + 1] - t.YP[d1][iy]);
                        if (d1 > d0 && run + piece > 128) break;
                        run += piece; ++d1;
                    }
                    if (run > 0) {
                        S.a[ns] = ((unsigned)iy << 16) | ((unsigned)X << 8) | (unsigned)(X + 1);
                        S.b[ns] = (1u << 31) | ((unsigned)d0 << 25) | ((unsigned)d1 << 19) | (unsigned)run;
                        ++ns;
                    }
                    d0 = d1;
                }
                ++X;
            } else {
                int X0 = X, run = 0;
                while (X < 125 && (X - X0) < 16 && cnt[X] <= 176 &&
                       (X == X0 || run + cnt[X] <= 128)) {
                    run += cnt[X]; ++X;
                }
                if (run > 0) {
                    S.a[ns] = ((unsigned)iy << 16) | ((unsigned)X0 << 8) | (unsigned)X;
                    S.b[ns] = ((unsigned)0 << 25) | ((unsigned)D << 19) | (unsigned)run;
                    ++ns;
                }
            }
        }
    }
    S.n = ns;
    return S;
}
constexpr SegTable g_raw = make_segs();

constexpr SegTable reorder_segs() {                  // heavy-first, 2 passes
    SegTable R{};
    int pos = 0;
    for (int i = 0; i < g_raw.n; ++i)
        if ((int)(g_raw.b[i] & 0x7FFFF) >= 120) { R.a[pos] = g_raw.a[i]; R.b[pos] = g_raw.b[i]; ++pos; }
    for (int i = 0; i < g_raw.n; ++i)
        if ((int)(g_raw.b[i] & 0x7FFFF) <  120) { R.a[pos] = g_raw.a[i]; R.b[pos] = g_raw.b[i]; ++pos; }
    R.n = pos;
    return R;
}
constexpr SegTable g_ct = reorder_segs();
constexpr int NSEG = g_ct.n;
static_assert(NSEG > 0 && NSEG <= 4096, "seg table overflow");
__device__ const SegTable g_segs = g_ct;

// ---------------------------------------------------------------- D1: mega
constexpr int PACK_BLOCKS = (C / 8) * (HW / 32);   // 1408
constexpr int SMAX_BLOCKS = NCOLS / 256;           // 66
constexpr int ZERO_TOTAL  = C * NBINS / 4;         // 500000 f4
constexpr int ZERO_BLOCKS = (ZERO_TOTAL + 1023) / 1024;  // 489
constexpr int MEGA_BLOCKS = PACK_BLOCKS + SMAX_BLOCKS + ZERO_BLOCKS;

__global__ void __launch_bounds__(256) mega_kernel(
        const float* __restrict__ feat,     // [NCAM][C][HW]
        const float* __restrict__ logits,   // [NCAM][D][HW]
        float* __restrict__ probs_t,
        unsigned short* __restrict__ feat_p,
        float* __restrict__ out) {
    __shared__ __align__(16) float tile[NCAM * 8 * 37];
    int b = blockIdx.x, t = threadIdx.x;

    if (b < PACK_BLOCKS) {
        int c0  = (b / 88) * 8;
        int hw0 = (b % 88) * 32;
        int cq = t >> 5, hwL = t & 31;
#pragma unroll
        for (int n = 0; n < NCAM; ++n)
            tile[(n * 8 + cq) * 37 + hwL] =
                feat[((size_t)(n * C + c0 + cq)) * HW + hw0 + hwL];
        __syncthreads();
        int hl = t >> 3, cL = t & 7;
        us8 v;
#pragma unroll
        for (int n = 0; n < NCAM; ++n)
            v[n] = f2bf(tile[(n * 8 + cL) * 37 + hl]);
        v[6] = 0; v[7] = 0;
        *(us8*)(feat_p + ((size_t)(hw0 + hl) * C + (c0 + cL)) * 8) = v;

    } else if (b < PACK_BLOCKS + SMAX_BLOCKS) {
        int col = (b - PACK_BLOCKS) * 256 + t;       // < NCOLS exact
        int n  = col / HW;
        int hw = col - n * HW;
        const float* src = logits + ((size_t)n * D) * HW + hw;
        float v[D];
        float m = -3.402823466e+38f;
#pragma unroll
        for (int d = 0; d < D; ++d) {
            v[d] = src[(size_t)d * HW];
            m = fmaxf(m, v[d]);
        }
        float s = 0.f;
#pragma unroll
        for (int d = 0; d < D; ++d) { v[d] = expf(v[d] - m); s += v[d]; }
        float inv = 1.0f / s;
#pragma unroll
        for (int d = 0; d < D; ++d)
            probs_t[(size_t)((d << 12) | hw) * 8 + n] = v[d] * inv;

    } else {
        int base = (b - PACK_BLOCKS - SMAX_BLOCKS) * 1024;
#pragma unroll
        for (int k = 0; k < 4; ++k) {
            int i = base + k * 256 + t;
            if (i < ZERO_TOTAL) ((f4*)out)[i] = f4{0.f, 0.f, 0.f, 0.f};
        }
    }
}

// ---------------------------------------------------------------- D2: gather
// Grid = NSEG*2, every block busy, heavy segments first. 128 thr = 2 waves
// (dgroups); lane = channel within chalf. Modulo-2 pipeline, group=3.
__global__ void __launch_bounds__(128, 4) gather_kernel(
        const unsigned short* __restrict__ feat_p,   // [hw][c][8] bf16
        const float* __restrict__ probs_t,           // [(d<<12)|hw][8] f32
        float* __restrict__ out) {                   // [C][NBINS]
    __shared__ float T[2][16][66];                   // 8.25 KB
    __shared__ unsigned list[LISTCAP];
    int slot  = blockIdx.x >> 1;
    int chalf = blockIdx.x & 1;
    unsigned da = g_segs.a[slot], db = g_segs.b[slot];
    int iy = da >> 16, X0 = (da >> 8) & 0xFF, X1 = da & 0xFF;
    int width = X1 - X0;
    bool split = (db >> 31) != 0;
    int d0 = (db >> 25) & 0x3F, d1 = (db >> 19) & 0x3F;
    int P  = (int)(db & 0x7FFFF);
    int t = threadIdx.x;

    if (t < 64) {                                    // wave 0: enumerate
        int d = d0 + t;
        if (d < d1) {
            int off = 0;
            for (int dd = d0; dd < d; ++dd)
                off += (g_tab.YP[dd][iy + 1] - g_tab.YP[dd][iy]) *
                       (g_tab.XP[dd][X1] - g_tab.XP[dd][X0]);
            int hb = g_tab.YP[d][iy], he = g_tab.YP[d][iy + 1];
            int p = off;
            for (int bl = 0; bl < width; ++bl) {
                int wb = g_tab.XP[d][X0 + bl], we = g_tab.XP[d][X0 + bl + 1];
                for (int h = hb; h < he; ++h)
                    for (int w = wb; w < we; ++w)
                        list[p++] = ((unsigned)bl << 18) | ((unsigned)d << 12)
                                  | (unsigned)(h * W + w);
            }
        }
    } else {                                         // wave 1: zero tiles
        float* Tf = &T[0][0][0];
        for (int i = t - 64; i < 2 * 16 * 66; i += 64) Tf[i] = 0.f;
    }
    __syncthreads();

    int lane = t & 63, dg = t >> 6;
    int c = chalf * 64 + lane;
    float* Tp = &T[dg][0][0];

    int npts = (P - dg + 1) >> 1;                    // this dgroup's count
    float racc = 0.f;
    int rbl = -1;

#define FETCH(I, BUF, P_)                                                     \
    { pk##BUF[I] = (unsigned)__shfl(myent, (P_));                             \
      fv##BUF[I] = *(const us8*)(feat_p +                                     \
                    (((size_t)(pk##BUF[I] & 0xFFFu) * C + (unsigned)c) * 8)); \
      const float* pp_ = probs_t + ((size_t)(pk##BUF[I] & 0x3FFFFu) << 3);    \
      pa##BUF[I] = *(const f4*)pp_; pb##BUF[I] = *(const f4*)(pp_ + 4); }
#define CONSUME(I, BUF)                                                       \
    { float s_ = pa##BUF[I].x * b2f(fv##BUF[I][0]) + pa##BUF[I].y * b2f(fv##BUF[I][1]) \
               + pa##BUF[I].z * b2f(fv##BUF[I][2]) + pa##BUF[I].w * b2f(fv##BUF[I][3]) \
               + pb##BUF[I].x * b2f(fv##BUF[I][4]) + pb##BUF[I].y * b2f(fv##BUF[I][5]);\
      int bl_ = (int)(pk##BUF[I] >> 18);                                      \
      if (bl_ != rbl) { if (rbl >= 0) Tp[rbl * 66 + lane] += racc;            \
                        rbl = bl_; racc = s_; }                               \
      else racc += s_; }

    int li0 = min(dg + 2 * lane, LISTCAP - 1);
    int myent_next = (int)list[li0];                 // window 0 entries
    for (int kb = 0; kb < npts; kb += 64) {
        int myent = myent_next;
        if (kb + 64 < npts) {                        // hoist next window's read
            int li = min(dg + 2 * (kb + 64 + lane), LISTCAP - 1);
            myent_next = (int)list[li];
        }
        int win = min(64, npts - kb);
        unsigned pkA[3], pkB[3]; us8 fvA[3], fvB[3];
        f4 paA[3], pbA[3], paB[3], pbB[3];
#pragma unroll
        for (int i = 0; i < 3; ++i) if (i < win) FETCH(i, A, i);
        for (int j = 0; j < win; j += 6) {
#pragma unroll
            for (int i = 0; i < 3; ++i) { int p = j + 3 + i;
                if (p < win) FETCH(i, B, p); }
#pragma unroll
            for (int i = 0; i < 3; ++i) { int p = j + i;
                if (p < win) CONSUME(i, A); }
#pragma unroll
            for (int i = 0; i < 3; ++i) { int p = j + 6 + i;
                if (p < win) FETCH(i, A, p); }
#pragma unroll
            for (int i = 0; i < 3; ++i) { int p = j + 3 + i;
                if (p < win) CONSUME(i, B); }
        }
    }
    if (rbl >= 0) Tp[rbl * 66 + lane] += racc;
    __syncthreads();
#undef FETCH
#undef CONSUME

    int binbase = iy * BEV + X0;
#pragma unroll
    for (int it = 0; it < 8; ++it) {                 // 16 bl x 8 cc per iter
        int bl = t & 15, cc = it * 8 + (t >> 4);     // cc in [0,64)
        if (bl < width) {
            float v = T[0][bl][cc] + T[1][bl][cc];
            float* dst = &out[(size_t)(chalf * 64 + cc) * NBINS + binbase + bl];
            if (split) atomicAdd(dst, v);
            else       *dst = v;
        }
    }
}

// ---------------------------------------------------------------- launch
extern "C" void kernel_launch(void* const* d_in, const int* in_sizes, int n_in,
                              void* d_out, int out_size, void* d_ws, size_t ws_size,
                              hipStream_t stream) {
    const float* img_feat     = (const float*)d_in[0];
    const float* depth_logits = (const float*)d_in[1];
    float* out = (float*)d_out;

    char* p = (char*)d_ws;
    float*          probs_t = (float*)p;          p += (size_t)D * 4096 * 8 * 4;  // 5.24 MB
    unsigned short* feat_p  = (unsigned short*)p; p += (size_t)HW * C * 8 * 2;    // 5.77 MB

    mega_kernel<<<MEGA_BLOCKS, 256, 0, stream>>>(
        img_feat, depth_logits, probs_t, feat_p, out);
    gather_kernel<<<NSEG * 2, 128, 0, stream>>>(feat_p, probs_t, out);
}